// Round 1
// baseline (79.250 us; speedup 1.0000x reference)
//
#include <hip/hip_runtime.h>

// Problem: A=1, B=32, M=32, H=1024, E=8, N=1024 (all fp32)
// out[b,e] = mask[b,e] * sum_h (sum_m hidden[b,m,h]) * (sum_n weight[e,h,n])
//
// ws layout (floats): [0, E*H)          wsum  (8192)
//                     [E*H, E*H + B*H)  hsum  (32768)

#define Bdim 32
#define Mdim 32
#define Hdim 1024
#define Edim 8
#define Ndim 1024

// Kernel A: both streaming reductions in one launch.
// blocks [0,512): weight rows (2048 waves x 4 rows, one wave per row of N=1024)
// blocks [512,640): hidden M-reduction, thread per (b,h), coalesced over h
__global__ __launch_bounds__(256) void reduce_kernel(
    const float* __restrict__ hidden,   // (B,M,H)
    const float* __restrict__ weight,   // (E,H,N)
    float* __restrict__ ws)
{
    constexpr int NB_W = 512;
    if (blockIdx.x < NB_W) {
        const int wave = blockIdx.x * 4 + (threadIdx.x >> 6);
        const int lane = threadIdx.x & 63;
        const float4* w4 = reinterpret_cast<const float4*>(weight);
        #pragma unroll
        for (int r = 0; r < 4; ++r) {
            const int row = wave * 4 + r;          // row = e*H + h, 0..8191
            float s = 0.f;
            #pragma unroll
            for (int j = 0; j < 4; ++j) {
                float4 v = w4[row * (Ndim / 4) + j * 64 + lane];
                s += (v.x + v.y) + (v.z + v.w);
            }
            #pragma unroll
            for (int off = 32; off > 0; off >>= 1)
                s += __shfl_xor(s, off, 64);
            if (lane == 0) ws[row] = s;
        }
    } else {
        const int idx = (blockIdx.x - NB_W) * 256 + threadIdx.x;  // b*H + h
        const int b = idx >> 10;
        const int h = idx & 1023;
        const float* p = hidden + b * (Mdim * Hdim) + h;
        float s = 0.f;
        #pragma unroll
        for (int m = 0; m < Mdim; ++m) s += p[m * Hdim];
        ws[Edim * Hdim + idx] = s;
    }
}

// Kernel B: 256 waves, one per (b,e); dot over h=1024 of hsum[b,:]*wsum[e,:],
// masked by sparsity[b,e].
__global__ __launch_bounds__(256) void dot_kernel(
    const float* __restrict__ ws,
    const float* __restrict__ sparsity,  // (B,E) flat
    float* __restrict__ out)             // (B,E) flat
{
    const int o = blockIdx.x * 4 + (threadIdx.x >> 6);   // b*E + e, 0..255
    const int lane = threadIdx.x & 63;
    const int b = o >> 3;
    const int e = o & 7;
    const float* hsum = ws + Edim * Hdim + b * Hdim;
    const float* wsum = ws + e * Hdim;
    float s = 0.f;
    #pragma unroll
    for (int j = 0; j < 16; ++j) {
        const int h = j * 64 + lane;
        s += hsum[h] * wsum[h];
    }
    #pragma unroll
    for (int off = 32; off > 0; off >>= 1)
        s += __shfl_xor(s, off, 64);
    if (lane == 0) out[o] = s * sparsity[o];
}

extern "C" void kernel_launch(void* const* d_in, const int* in_sizes, int n_in,
                              void* d_out, int out_size, void* d_ws, size_t ws_size,
                              hipStream_t stream) {
    const float* hidden   = (const float*)d_in[0];  // (1,32,32,1024)
    const float* sparsity = (const float*)d_in[1];  // (1,32,1,8)
    const float* weight   = (const float*)d_in[2];  // (1,8,1024,1024)
    float* out = (float*)d_out;                     // (1,32,8)
    float* ws  = (float*)d_ws;

    reduce_kernel<<<640, 256, 0, stream>>>(hidden, weight, ws);
    dot_kernel<<<64, 256, 0, stream>>>(ws, sparsity, out);
}